// Round 8
// baseline (122.187 us; speedup 1.0000x reference)
//
#include <hip/hip_runtime.h>
#include <hip/hip_fp16.h>

// MinGRU, round 8: ONE kernel, one x-read, whole-H blocks.
// Grid 256 blocks (8 b-chains x 32 time-tiles) x 1024 threads = exactly one
// block per CU -> co-residency guaranteed regardless of dispatch order.
// Per block: x fp32 tile (128x256) loaded once coalesced -> bf16 -> swizzled
// LDS (full K resident); W fp32 staged per BK=32 slice via global_load_lds
// (L2-hot); 16 waves = 2 mats x 2 rowgrps x 4 colgrps, 16x16x32 bf16 MFMA
// (validated layout); epilogue writes (z,u) fp16 half2 into 128KB LDS overlay;
// scan transforms in-place to (a,bb); payload-in-atomic lookback (LSB=1 ready,
// 0xAA poison has LSB=0 so NO mailbox zeroing needed); apply writes out.
// LDS 140288 B dynamic (gfx950 group segment max = 160 KiB).

namespace {
constexpr int kB  = 8;
constexpr int kT  = 4096;
constexpr int kD  = 256;
constexpr int kH  = 256;
constexpr int TM  = 128;           // time rows per block
constexpr int kNT = kT / TM;       // 32 tiles per chain
constexpr int SMEM_BYTES = 140288; // max(staging 128K, zu 128K) + sub 8K + hs 1K
}

typedef short s16x8 __attribute__((ext_vector_type(8)));
typedef short s16x4 __attribute__((ext_vector_type(4)));
typedef float f32x4 __attribute__((ext_vector_type(4)));

__device__ __forceinline__ short f2bf(float f) {
    union { float f; unsigned int u; } v; v.f = f;
    unsigned int r = v.u + 0x7fffu + ((v.u >> 16) & 1u);   // RNE
    return (short)(r >> 16);
}

__device__ __forceinline__ void load_lds16(const void* g, void* l) {
    __builtin_amdgcn_global_load_lds(
        (const __attribute__((address_space(1))) void*)g,
        (__attribute__((address_space(3))) void*)l, 16, 0, 0);
}

__global__ __launch_bounds__(1024)
void mingru_fused(const float* __restrict__ x,
                  const float* __restrict__ h0,
                  const float* __restrict__ Wz,
                  const float* __restrict__ bz,
                  const float* __restrict__ Wh,
                  const float* __restrict__ bh,
                  unsigned long long* __restrict__ agg,   // [8][32][256]
                  float* __restrict__ out)
{
    extern __shared__ __align__(16) unsigned char smem[];
    // K-loop live:  Xb bf16 [128][256] swizzled @0 (64K) | Wst fp32 [2][256][32] @64K (64K)
    // post-loop:    zu half2 [128][256] @0 (128K) | sub float2[4][256] @128K | hs float[256] @136K+...
    unsigned short* Xb = (unsigned short*)smem;
    float* Wst         = (float*)(smem + 65536);
    __half2* zu        = (__half2*)smem;
    float2* sub_lds    = (float2*)(smem + 131072);
    float*  hs_lds     = (float*)(smem + 139264);

    const int tid  = threadIdx.x;
    const int lane = tid & 63;
    const int wv   = tid >> 6;        // 0..15
    const int ln15 = lane & 15;
    const int quad = lane >> 4;
    const int mat  = wv & 1;          // 0 = Wz/z, 1 = Wh/u
    const int rowg = (wv >> 1) & 1;   // 64-row half
    const int colg = wv >> 2;         // 64-col group (0..3)

    const int b    = blockIdx.x;      // chain 0..7
    const int t    = blockIdx.y;      // tile 0..31
    const int row0 = b * kT + t * TM;

    // ---- stage W slice (BK=32 fp32, both mats), XOR-swizzled 16B blocks.
    auto stageW = [&](int it) {
        #pragma unroll
        for (int s2 = 0; s2 < 2; ++s2) {
            const int seg = wv * 2 + s2;          // 0..31 (8 rows x 128B each)
            const int r   = seg * 8 + (lane >> 3);
            const int blk = (lane & 7) ^ (r & 7);
            const size_t go = (size_t)r * kD + it * 32 + blk * 4;
            load_lds16(Wz + go, (char*)Wst + seg * 1024);
            load_lds16(Wh + go, (char*)Wst + 32768 + seg * 1024);
        }
    };

    // ---- load full x tile fp32 (coalesced: wave covers one 1KB row per w),
    // convert to bf16, write swizzled LDS.
    float4 xv[8];
    #pragma unroll
    for (int w = 0; w < 8; ++w) {
        const int r = w * 16 + wv;                // 0..127
        xv[w] = *(const float4*)(x + (size_t)(row0 + r) * kD + lane * 4);
    }
    stageW(0);
    #pragma unroll
    for (int w = 0; w < 8; ++w) {
        const int r = w * 16 + wv;
        s16x4 p;
        p[0] = f2bf(xv[w].x); p[1] = f2bf(xv[w].y);
        p[2] = f2bf(xv[w].z); p[3] = f2bf(xv[w].w);
        const int c    = lane >> 1;               // 16B block 0..31
        const int slot = c ^ (r & 7);
        *(s16x4*)((char*)Xb + r * 512 + slot * 16 + (lane & 1) * 8) = p;
    }
    __syncthreads();

    // ---- K loop: 8 iters of BK=32; Xb resident full-K; W restaged per iter.
    f32x4 acc[4][4] = {};                         // [mt][nt], one matrix per wave
    const float* Wmat = Wst + mat * 8192;
    for (int it = 0; it < 8; ++it) {
        s16x8 af[4];
        #pragma unroll
        for (int mt = 0; mt < 4; ++mt) {
            const int r = rowg * 64 + mt * 16 + ln15;
            const int c = it * 4 + quad;          // 16B block in full-K row
            af[mt] = *(const s16x8*)((char*)Xb + r * 512 + ((c ^ (r & 7)) << 4));
        }
        #pragma unroll
        for (int nt = 0; nt < 4; ++nt) {
            const int h = colg * 64 + nt * 16 + ln15;
            const float* wr_ = Wmat + h * 32;
            const f32x4 lo = *(const f32x4*)&wr_[((2 * quad)     ^ (h & 7)) << 2];
            const f32x4 hi = *(const f32x4*)&wr_[((2 * quad + 1) ^ (h & 7)) << 2];
            s16x8 bf;
            bf[0] = f2bf(lo[0]); bf[1] = f2bf(lo[1]); bf[2] = f2bf(lo[2]); bf[3] = f2bf(lo[3]);
            bf[4] = f2bf(hi[0]); bf[5] = f2bf(hi[1]); bf[6] = f2bf(hi[2]); bf[7] = f2bf(hi[3]);
            #pragma unroll
            for (int mt = 0; mt < 4; ++mt)
                acc[mt][nt] = __builtin_amdgcn_mfma_f32_16x16x32_bf16(
                    af[mt], bf, acc[mt][nt], 0, 0, 0);
        }
        __syncthreads();                          // done reading Wst
        if (it < 7) stageW(it + 1);
        __syncthreads();                          // staged (drain)
    }

    // ---- epilogue: z+bz / u+bh -> zu LDS fp16 (C/D: col=ln15, row=quad*4+r)
    {
        const float* bias = mat ? bh : bz;
        #pragma unroll
        for (int nt = 0; nt < 4; ++nt) {
            const int h  = colg * 64 + nt * 16 + ln15;
            const float bv = bias[h];
            #pragma unroll
            for (int mt = 0; mt < 4; ++mt) {
                const int tr0 = rowg * 64 + mt * 16 + quad * 4;
                #pragma unroll
                for (int r = 0; r < 4; ++r) {
                    __half* cell = (__half*)&zu[(tr0 + r) * 256 + h];
                    cell[mat] = __float2half_rn(acc[mt][nt][r] + bv);
                }
            }
        }
    }
    __syncthreads();

    // ---- scan: transform (z,u) -> (a,bb) in place + sub-chunk affine summary
    const int s = tid >> 8;                       // sub-chunk 0..3 (32 rows)
    const int h = tid & 255;
    {
        float A = 1.0f, Bv = 0.0f;
        #pragma unroll 8
        for (int r = 0; r < 32; ++r) {
            const int tr = s * 32 + r;
            const __half2 v = zu[tr * 256 + h];
            const float z = __low2float(v), u = __high2float(v);
            const float g = 1.0f / (1.0f + __expf(-z));
            const float a = 1.0f - g, bb = g * u;
            zu[tr * 256 + h] = __floats2half2_rn(a, bb);
            Bv = fmaf(a, Bv, bb);
            A *= a;
        }
        float2 o; o.x = A; o.y = Bv;
        sub_lds[s * 256 + h] = o;
    }
    __syncthreads();

    // ---- publish block aggregate + batched lookback (tid<256, one per h)
    if (tid < 256) {
        float A = 1.0f, Bv = 0.0f;
        #pragma unroll
        for (int s2 = 0; s2 < 4; ++s2) {
            const float2 g = sub_lds[s2 * 256 + tid];
            Bv = fmaf(g.x, Bv, g.y);
            A *= g.x;
        }
        union { float2 f; unsigned long long u; } pk;
        pk.f.x = A; pk.f.y = Bv;
        pk.u |= 1ull;                             // LSB=1 => ready (poison/zero have LSB=0)
        __hip_atomic_store(&agg[(size_t)(b * kNT + t) * 256 + tid], pk.u,
                           __ATOMIC_RELAXED, __HIP_MEMORY_SCOPE_AGENT);

        float hs = h0[(size_t)b * kH + tid];
        for (int j0 = 0; j0 < t; j0 += 8) {
            const int nb = (t - j0 < 8) ? (t - j0) : 8;
            unsigned long long u[8];
            #pragma unroll
            for (int q = 0; q < 8; ++q)
                if (q < nb)
                    u[q] = __hip_atomic_load(
                        &agg[(size_t)(b * kNT + j0 + q) * 256 + tid],
                        __ATOMIC_RELAXED, __HIP_MEMORY_SCOPE_AGENT);
            #pragma unroll
            for (int q = 0; q < 8; ++q) {
                if (q < nb) {
                    while ((u[q] & 1ull) == 0ull)
                        u[q] = __hip_atomic_load(
                            &agg[(size_t)(b * kNT + j0 + q) * 256 + tid],
                            __ATOMIC_RELAXED, __HIP_MEMORY_SCOPE_AGENT);
                    union { unsigned long long u; float2 f; } qk; qk.u = u[q];
                    hs = fmaf(qk.f.x, hs, qk.f.y);
                }
            }
        }
        hs_lds[tid] = hs;
    }
    __syncthreads();

    // ---- apply recurrence for this thread's 32 rows; write out
    {
        float hv = hs_lds[h];
        #pragma unroll
        for (int s2 = 0; s2 < 4; ++s2)
            if (s2 < s) {
                const float2 g = sub_lds[s2 * 256 + h];
                hv = fmaf(g.x, hv, g.y);
            }
        const size_t obase = (size_t)(row0 + s * 32) * kH + h;
        #pragma unroll 8
        for (int r = 0; r < 32; ++r) {
            const __half2 v = zu[(s * 32 + r) * 256 + h];
            hv = fmaf(__low2float(v), hv, __high2float(v));
            out[obase + (size_t)r * kH] = hv;
        }
    }
}

extern "C" void kernel_launch(void* const* d_in, const int* in_sizes, int n_in,
                              void* d_out, int out_size, void* d_ws, size_t ws_size,
                              hipStream_t stream)
{
    const float* x  = (const float*)d_in[0];
    const float* h0 = (const float*)d_in[1];
    const float* Wz = (const float*)d_in[2];
    const float* bz = (const float*)d_in[3];
    const float* Wh = (const float*)d_in[4];
    const float* bh = (const float*)d_in[5];
    float* out = (float*)d_out;

    unsigned long long* agg = (unsigned long long*)d_ws;   // 512 KB mailbox

    (void)hipFuncSetAttribute((const void*)mingru_fused,
                              hipFuncAttributeMaxDynamicSharedMemorySize,
                              SMEM_BYTES);
    mingru_fused<<<dim3(kB, kNT), 1024, SMEM_BYTES, stream>>>(
        x, h0, Wz, bz, Wh, bh, agg, out);
}